// Round 15
// baseline (6151.211 us; speedup 1.0000x reference)
//
#include <hip/hip_runtime.h>
#include <cmath>

#define kB 256
#define kS 512
#define kI 128
#define kH 256

typedef __attribute__((ext_vector_type(8))) short short8;
typedef __attribute__((ext_vector_type(2))) short short2v;
typedef __attribute__((ext_vector_type(4))) float f32x4;
typedef unsigned long long u64;

#define AS_STRIDE 408  // bf16 elems; row stride 816B
#define GSTR 18        // scratch row stride in floats (<=2-way banks = free)

// ws: hx u64[2 parity][16 grp][16 b][256 hh] = 1 MiB.
//   u64 = (seq16 << 48) | (hi << 32) | (mid << 16) | lo   (producer-packed split)
#define WS_HX_U64 (2 * 16 * 16 * 256)

__device__ __forceinline__ float sigmoidf_(float z) { return 1.0f / (1.0f + expf(-z)); }

__device__ __forceinline__ unsigned short f2b(float f) {
  unsigned u = __builtin_bit_cast(unsigned, f);
  unsigned r = (u + 0x7fffu + ((u >> 16) & 1u)) >> 16;
  return (unsigned short)r;
}
__device__ __forceinline__ float b2f(unsigned short s) {
  unsigned u = ((unsigned)s) << 16;
  return __builtin_bit_cast(float, u);
}
__device__ __forceinline__ void bsplit2(float f, unsigned short& h_, unsigned short& l_) {
  h_ = f2b(f);
  l_ = f2b(f - b2f(h_));
}
__device__ __forceinline__ void bsplit3(float f, unsigned short& h_, unsigned short& m_, unsigned short& l_) {
  h_ = f2b(f);
  float r1 = f - b2f(h_);
  m_ = f2b(r1);
  l_ = f2b(r1 - b2f(m_));
}

// Coalesced transposed poll of 4 rows at one column; batched stale-retry.
__device__ __forceinline__ void pollrow4(const u64* grp, int col, int rbase,
                                         unsigned seq16, u64* u) {
  unsigned miss = 0xfu;
  for (;;) {
    unsigned nm = 0;
#pragma unroll
    for (int j = 0; j < 4; ++j)
      if (miss & (1u << j))
        u[j] = __hip_atomic_load(grp + (size_t)(rbase + j) * 256 + col,
                                 __ATOMIC_RELAXED, __HIP_MEMORY_SCOPE_SYSTEM);
#pragma unroll
    for (int j = 0; j < 4; ++j)
      if ((miss & (1u << j)) && (unsigned)(u[j] >> 48) != seq16) nm |= 1u << j;
    if (!nm) return;
    miss = nm;
    __builtin_amdgcn_s_sleep(1);
  }
}

// 16-wave block (1024 thr), group = 8 blocks (straggler domain 8).
// Wave w = (gate g=w&3, K-quarter kh=w>>2) computes BOTH 16-hh subtiles:
// each A-fragment ds_read feeds 4 MFMAs (144 A-reads/block-step, 2x fewer
// than r13) and weights are 18 short8 = 72 VGPRs -> fits the 128-VGPR cap
// of 4 waves/SIMD natively (r13/r14 spilled ~60 regs to scratch).
// Accs merged by magnitude: P=ah*wh, Q1={ah*wm,am*wh}, Q2={ah*wl,am*wm,al*wh};
// d = P + (Q1 + Q2); cell sums the 4 kh partials (p0+p1)+(p2+p3).
__global__ void __launch_bounds__(1024)
lstm_mfma(const float* __restrict__ x,
          const float* __restrict__ enc_Wx, const float* __restrict__ enc_bx,
          const float* __restrict__ enc_Wh, const float* __restrict__ enc_bh,
          const float* __restrict__ enc_b,
          const float* __restrict__ dec_Wx, const float* __restrict__ dec_bx,
          const float* __restrict__ dec_Wh, const float* __restrict__ dec_bh,
          const float* __restrict__ dec_b,
          const float* __restrict__ rec_W, const float* __restrict__ rec_b,
          float* __restrict__ out,
          u64* __restrict__ hx) {
  __shared__ __align__(16) short As_h[16 * AS_STRIDE];
  __shared__ __align__(16) short As_m[16 * AS_STRIDE];
  __shared__ __align__(16) short As_l[16 * AS_STRIDE];
  __shared__ float g_scr[32 * 16 * GSTR];   // 32 partial tiles (kh,g,st)
  __shared__ float r_scr[16 * 16 * GSTR];   // 16 rec tiles (st,kst)
  __shared__ float red[16][64];
  __shared__ float maskS[16];

  const int tid = threadIdx.x;
  // XCD-colocating decode: a group's 8 blocks are blk ≡ bt (mod 16) -> same
  // XCD under round-robin. Pure perf; protocol stays system-scope.
  const int bt = blockIdx.x & 15;   // b-group (16 rows)
  const int ht = blockIdx.x >> 4;   // hh-slice (0..7, 32 hh each)
  const int b0 = bt << 4, hh0 = ht << 5;
  const int w  = tid >> 6;          // wave: g = w&3, kh = w>>2
  const int g  = w & 3;
  const int kh = w >> 2;
  const int l  = tid & 63;
  const int fr = l & 15;            // MFMA frag row/col
  const int gq = l >> 4;            // MFMA k-subgroup
  const int cb = (tid & 511) >> 5;  // cell: local b row (tid<512)
  const int cq = tid & 31;          // cell: hh-local
  const int hhc = hh0 + cq;
  const int col  = tid & 255;       // staging: column
  const int rbase = (tid >> 8) * 4; // staging: 4-row quarter

  // ---- combined biases (cell threads tid<512) ----
  float be0 = enc_bx[0*kH+hhc] + enc_bh[0*kH+hhc] + enc_b[0*kH+hhc];
  float be1 = enc_bx[1*kH+hhc] + enc_bh[1*kH+hhc] + enc_b[1*kH+hhc];
  float be2 = enc_bx[2*kH+hhc] + enc_bh[2*kH+hhc] + enc_b[2*kH+hhc];
  float be3 = enc_bx[3*kH+hhc] + enc_bh[3*kH+hhc] + enc_b[3*kH+hhc];
  float bd0 = dec_bx[0*kH+hhc] + dec_bh[0*kH+hhc] + dec_b[0*kH+hhc];
  float bd1 = dec_bx[1*kH+hhc] + dec_bh[1*kH+hhc] + dec_b[1*kH+hhc];
  float bd2 = dec_bx[2*kH+hhc] + dec_bh[2*kH+hhc] + dec_b[2*kH+hhc];
  float bd3 = dec_bx[3*kH+hhc] + dec_bh[3*kH+hhc] + dec_b[3*kH+hhc];
  float recb = (ht < 4) ? rec_b[ht * 32 + cq] : 0.0f;
  float creg = 0.0f;

  // ---- encoder weights: wave (g,kh) x 2 subtiles x 3 ksteps, 3-way split ----
  short8 wfh[2][3], wfm[2][3], wfl[2][3];
#pragma unroll
  for (int st = 0; st < 2; ++st)
#pragma unroll
  for (int kl = 0; kl < 3; ++kl) {
    int k = (kh * 3 + kl) * 32 + gq * 8;
    const int hw = hh0 + st * 16 + fr;
    const float* src = (k < 128)
        ? (enc_Wx + ((size_t)(g * kH) + hw) * kI + k)
        : (enc_Wh + ((size_t)(g * kH) + hw) * kH + (k - 128));
    short8 hi, mi, lo;
#pragma unroll
    for (int j = 0; j < 8; ++j) {
      unsigned short h_, m_, l_;
      bsplit3(src[j], h_, m_, l_);
      hi[j] = (short)h_; mi[j] = (short)m_; lo[j] = (short)l_;
    }
    wfh[st][kl] = hi; wfm[st][kl] = mi; wfl[st][kl] = lo;
  }

  // ================= encoder: 512 steps =================
  for (int s = 0; s < kS; ++s) {
    const int par = s & 1;
    // stage x: 1024 threads x 2 floats (row tid>>6, cols (tid&63)*2..+1)
    {
      const int xb = tid >> 6, xc = (tid & 63) * 2;
      const float* xp = x + ((size_t)(b0 + xb) * kS + s) * kI + xc;
      float v0 = xp[0], v1 = xp[1];
      unsigned short h0, m0, l0, h1, m1, l1;
      bsplit3(v0, h0, m0, l0);
      bsplit3(v1, h1, m1, l1);
      short2v hv = {(short)h0, (short)h1}, mv = {(short)m0, (short)m1}, lv = {(short)l0, (short)l1};
      *(short2v*)(As_h + xb * AS_STRIDE + xc) = hv;
      *(short2v*)(As_m + xb * AS_STRIDE + xc) = mv;
      *(short2v*)(As_l + xb * AS_STRIDE + xc) = lv;
      red[xb][tid & 63] = v0 * v0 + v1 * v1;
    }
    // stage h: coalesced poll of producer-packed splits (4 rows per thread)
    {
      const u64* grp = hx + ((size_t)(par * 16 + bt) * 16) * 256;
      u64 u[4];
      pollrow4(grp, col, rbase, (unsigned)(s & 0xffff), u);
#pragma unroll
      for (int j = 0; j < 4; ++j) {
        As_h[(rbase + j) * AS_STRIDE + 128 + col] = (short)(unsigned short)(u[j] >> 32);
        As_m[(rbase + j) * AS_STRIDE + 128 + col] = (short)(unsigned short)(u[j] >> 16);
        As_l[(rbase + j) * AS_STRIDE + 128 + col] = (short)(unsigned short)(u[j]);
      }
    }
    __syncthreads();  // B
    if (tid < 16) {
      float ss = 0.f;
#pragma unroll
      for (int j = 0; j < 64; ++j) ss += red[tid][j];
      maskS[tid] = (ss > 1e-6f) ? 1.0f : 0.0f;
    }
    // gate GEMM: ksteps kh*3..kh*3+2, both subtiles share each A-read
    f32x4 aP[2], aQ1[2], aQ2[2];
#pragma unroll
    for (int st = 0; st < 2; ++st) {
      aP[st] = (f32x4){0.f, 0.f, 0.f, 0.f}; aQ1[st] = aP[st]; aQ2[st] = aP[st];
    }
#pragma unroll
    for (int kl = 0; kl < 3; ++kl) {
      const int ko = (kh * 3 + kl) * 32 + gq * 8;
      const short8 ah = *(const short8*)(As_h + fr * AS_STRIDE + ko);
      const short8 am = *(const short8*)(As_m + fr * AS_STRIDE + ko);
      const short8 al = *(const short8*)(As_l + fr * AS_STRIDE + ko);
#pragma unroll
      for (int st = 0; st < 2; ++st) {
        aP[st]  = __builtin_amdgcn_mfma_f32_16x16x32_bf16(ah, wfh[st][kl], aP[st], 0, 0, 0);
        aQ1[st] = __builtin_amdgcn_mfma_f32_16x16x32_bf16(ah, wfm[st][kl], aQ1[st], 0, 0, 0);
        aQ1[st] = __builtin_amdgcn_mfma_f32_16x16x32_bf16(am, wfh[st][kl], aQ1[st], 0, 0, 0);
        aQ2[st] = __builtin_amdgcn_mfma_f32_16x16x32_bf16(ah, wfl[st][kl], aQ2[st], 0, 0, 0);
        aQ2[st] = __builtin_amdgcn_mfma_f32_16x16x32_bf16(am, wfm[st][kl], aQ2[st], 0, 0, 0);
        aQ2[st] = __builtin_amdgcn_mfma_f32_16x16x32_bf16(al, wfh[st][kl], aQ2[st], 0, 0, 0);
      }
    }
#pragma unroll
    for (int st = 0; st < 2; ++st) {
      f32x4 d = aP[st] + (aQ1[st] + aQ2[st]);
      const int ti = (kh * 4 + g) * 2 + st;
#pragma unroll
      for (int i = 0; i < 4; ++i) g_scr[(ti * 16 + gq * 4 + i) * GSTR + fr] = d[i];
    }
    __syncthreads();  // C
    // cell update (tid<512 owns (cb,hhc)): sum 4 kh partials per gate
    if (tid < 512) {
      const int st = cq >> 4, fq = cq & 15;
#define GS(KH, GG) g_scr[((((KH) * 4 + (GG)) * 2 + st) * 16 + cb) * GSTR + fq]
      float gf = (GS(0,0) + GS(1,0)) + (GS(2,0) + GS(3,0)) + be0;
      float gi = (GS(0,1) + GS(1,1)) + (GS(2,1) + GS(3,1)) + be1;
      float go = (GS(0,2) + GS(1,2)) + (GS(2,2) + GS(3,2)) + be2;
      float gc = (GS(0,3) + GS(1,3)) + (GS(2,3) + GS(3,3)) + be3;
      float m  = maskS[cb];
      float f_ = sigmoidf_(gf), i_ = sigmoidf_(gi), o_ = sigmoidf_(go);
      float ct = tanhf(gc);
      creg = (f_ + i_) * creg + m * (i_ * ct);
      float hval = o_ * tanhf(creg);
      unsigned short hb, mb2, lb;
      bsplit3(hval, hb, mb2, lb);
      u64 pk = ((u64)(unsigned)((s + 1) & 0xffff) << 48) | ((u64)hb << 32) | ((u64)mb2 << 16) | (u64)lb;
      size_t wi = (((size_t)(((s + 1) & 1) * 16 + bt) * 16 + cb) * 256) + hhc;
      __hip_atomic_store(hx + wi, pk, __ATOMIC_RELAXED, __HIP_MEMORY_SCOPE_SYSTEM);
    }
  }

  // ---- decoder weights: wdc = dec_Wx + dec_Wh; wave (g,kh) x 2 st x 2 ksteps ----
  short8 dwh[2][2], dwm[2][2], dwl[2][2];
#pragma unroll
  for (int st = 0; st < 2; ++st)
#pragma unroll
  for (int kl = 0; kl < 2; ++kl) {
    int k = (kh * 2 + kl) * 32 + gq * 8;
    const int hw = hh0 + st * 16 + fr;
    const float* s1 = dec_Wx + ((size_t)(g * kH) + hw) * kH + k;
    const float* s2 = dec_Wh + ((size_t)(g * kH) + hw) * kH + k;
    short8 hi, mi, lo;
#pragma unroll
    for (int j = 0; j < 8; ++j) {
      unsigned short h_, m_, l_;
      bsplit3(s1[j] + s2[j], h_, m_, l_);
      hi[j] = (short)h_; mi[j] = (short)m_; lo[j] = (short)l_;
    }
    dwh[st][kl] = hi; dwm[st][kl] = mi; dwl[st][kl] = lo;
  }
  // rec weights (ht<4): wave w -> (kstR = w&7, stR = w>>3)
  const int kstR = w & 7, stR = w >> 3;
  short8 rfh, rfl;
  {
    short8 hi = {0,0,0,0,0,0,0,0}, lo = hi;
    if (ht < 4) {
      int k = kstR * 32 + gq * 8;
      const float* src = rec_W + ((size_t)(ht * 32 + stR * 16 + fr)) * kH + k;
#pragma unroll
      for (int j = 0; j < 8; ++j) {
        unsigned short h_, l_;
        bsplit2(src[j], h_, l_);
        hi[j] = (short)h_; lo[j] = (short)l_;
      }
    }
    rfh = hi; rfl = lo;
  }

  // ================= decoder: 512 steps =================
  for (int t = 0; t < kS; ++t) {
    const int s = kS + t;
    const int par = s & 1;
    // stage h coalesced (col offset 0)
    {
      const u64* grp = hx + ((size_t)(par * 16 + bt) * 16) * 256;
      u64 u[4];
      pollrow4(grp, col, rbase, (unsigned)(s & 0xffff), u);
#pragma unroll
      for (int j = 0; j < 4; ++j) {
        As_h[(rbase + j) * AS_STRIDE + col] = (short)(unsigned short)(u[j] >> 32);
        As_m[(rbase + j) * AS_STRIDE + col] = (short)(unsigned short)(u[j] >> 16);
        As_l[(rbase + j) * AS_STRIDE + col] = (short)(unsigned short)(u[j]);
      }
    }
    __syncthreads();  // B1
    // silence-mask partials from LDS reconstruction (4 elems/thread)
    {
      const int mb = tid >> 6, c0 = (tid & 63) * 4;
      float ss = 0.f;
#pragma unroll
      for (int j = 0; j < 4; ++j) {
        float v = b2f((unsigned short)As_h[mb * AS_STRIDE + c0 + j])
                + b2f((unsigned short)As_m[mb * AS_STRIDE + c0 + j])
                + b2f((unsigned short)As_l[mb * AS_STRIDE + c0 + j]);
        ss += v * v;
      }
      red[mb][tid & 63] = ss;
    }
    __syncthreads();  // B2
    if (tid < 16) {
      float ss = 0.f;
#pragma unroll
      for (int j = 0; j < 64; ++j) ss += red[tid][j];
      maskS[tid] = (ss > 1e-6f) ? 1.0f : 0.0f;
    }
    // gate GEMM: ksteps kh*2..kh*2+1, both subtiles share each A-read
    f32x4 aP[2], aQ1[2], aQ2[2];
#pragma unroll
    for (int st = 0; st < 2; ++st) {
      aP[st] = (f32x4){0.f, 0.f, 0.f, 0.f}; aQ1[st] = aP[st]; aQ2[st] = aP[st];
    }
#pragma unroll
    for (int kl = 0; kl < 2; ++kl) {
      const int ko = (kh * 2 + kl) * 32 + gq * 8;
      const short8 ah = *(const short8*)(As_h + fr * AS_STRIDE + ko);
      const short8 am = *(const short8*)(As_m + fr * AS_STRIDE + ko);
      const short8 al = *(const short8*)(As_l + fr * AS_STRIDE + ko);
#pragma unroll
      for (int st = 0; st < 2; ++st) {
        aP[st]  = __builtin_amdgcn_mfma_f32_16x16x32_bf16(ah, dwh[st][kl], aP[st], 0, 0, 0);
        aQ1[st] = __builtin_amdgcn_mfma_f32_16x16x32_bf16(ah, dwm[st][kl], aQ1[st], 0, 0, 0);
        aQ1[st] = __builtin_amdgcn_mfma_f32_16x16x32_bf16(am, dwh[st][kl], aQ1[st], 0, 0, 0);
        aQ2[st] = __builtin_amdgcn_mfma_f32_16x16x32_bf16(ah, dwl[st][kl], aQ2[st], 0, 0, 0);
        aQ2[st] = __builtin_amdgcn_mfma_f32_16x16x32_bf16(am, dwm[st][kl], aQ2[st], 0, 0, 0);
        aQ2[st] = __builtin_amdgcn_mfma_f32_16x16x32_bf16(al, dwh[st][kl], aQ2[st], 0, 0, 0);
      }
    }
#pragma unroll
    for (int st = 0; st < 2; ++st) {
      f32x4 d = aP[st] + (aQ1[st] + aQ2[st]);
      const int ti = (kh * 4 + g) * 2 + st;
#pragma unroll
      for (int i = 0; i < 4; ++i) g_scr[(ti * 16 + gq * 4 + i) * GSTR + fr] = d[i];
    }
    __syncthreads();  // C
    // cell update + publish FIRST (critical path), rec-GEMM after
    if (tid < 512) {
      const int st = cq >> 4, fq = cq & 15;
      float gf = (GS(0,0) + GS(1,0)) + (GS(2,0) + GS(3,0)) + bd0;
      float gi = (GS(0,1) + GS(1,1)) + (GS(2,1) + GS(3,1)) + bd1;
      float go = (GS(0,2) + GS(1,2)) + (GS(2,2) + GS(3,2)) + bd2;
      float gc = (GS(0,3) + GS(1,3)) + (GS(2,3) + GS(3,3)) + bd3;
      float m  = maskS[cb];
      float f_ = sigmoidf_(gf), i_ = sigmoidf_(gi), o_ = sigmoidf_(go);
      float ct = tanhf(gc);
      creg = (f_ + i_) * creg + m * (i_ * ct);
      float hval = o_ * tanhf(creg);
      unsigned short hb, mb2, lb;
      bsplit3(hval, hb, mb2, lb);
      u64 pk = ((u64)(unsigned)((s + 1) & 0xffff) << 48) | ((u64)hb << 32) | ((u64)mb2 << 16) | (u64)lb;
      size_t wi = (((size_t)(((s + 1) & 1) * 16 + bt) * 16 + cb) * 256) + hhc;
      __hip_atomic_store(hx + wi, pk, __ATOMIC_RELAXED, __HIP_MEMORY_SCOPE_SYSTEM);
    }
    // rec-GEMM (off critical path): wave w does (kstR, stR) on staged h_(t-1)
    if (ht < 4) {
      const int ko = kstR * 32 + gq * 8;
      const short8 ah = *(const short8*)(As_h + fr * AS_STRIDE + ko);
      const short8 am = *(const short8*)(As_m + fr * AS_STRIDE + ko);
      f32x4 r0 = {0.f,0.f,0.f,0.f}, r1 = r0, r2 = r0;
      r0 = __builtin_amdgcn_mfma_f32_16x16x32_bf16(ah, rfh, r0, 0, 0, 0);
      r1 = __builtin_amdgcn_mfma_f32_16x16x32_bf16(ah, rfl, r1, 0, 0, 0);
      r2 = __builtin_amdgcn_mfma_f32_16x16x32_bf16(am, rfh, r2, 0, 0, 0);
      f32x4 rd = r0 + r1 + r2;
#pragma unroll
      for (int i = 0; i < 4; ++i) r_scr[(w * 16 + gq * 4 + i) * GSTR + fr] = rd[i];
    }
    __syncthreads();  // D: r_scr ready; As free for next staging
    if (ht < 4 && t > 0 && tid < 512) {
      const int st = cq >> 4, fq = cq & 15;
      float rsum = recb;
#pragma unroll
      for (int kk = 0; kk < 8; ++kk)
        rsum += r_scr[((st * 8 + kk) * 16 + cb) * GSTR + fq];
      __builtin_nontemporal_store(rsum, &out[((size_t)(b0 + cb) * kS + (t - 1)) * kI + ht * 32 + cq]);
    }
  }

  // ================= final rec: out[:, 511, :] =================
  {
    {
      const u64* grp = hx + ((size_t)(0 * 16 + bt) * 16) * 256;
      u64 u[4];
      pollrow4(grp, col, rbase, (unsigned)((2 * kS) & 0xffff), u);
#pragma unroll
      for (int j = 0; j < 4; ++j) {
        As_h[(rbase + j) * AS_STRIDE + col] = (short)(unsigned short)(u[j] >> 32);
        As_m[(rbase + j) * AS_STRIDE + col] = (short)(unsigned short)(u[j] >> 16);
      }
    }
    __syncthreads();
    if (ht < 4) {
      const int ko = kstR * 32 + gq * 8;
      const short8 ah = *(const short8*)(As_h + fr * AS_STRIDE + ko);
      const short8 am = *(const short8*)(As_m + fr * AS_STRIDE + ko);
      f32x4 r0 = {0.f,0.f,0.f,0.f}, r1 = r0, r2 = r0;
      r0 = __builtin_amdgcn_mfma_f32_16x16x32_bf16(ah, rfh, r0, 0, 0, 0);
      r1 = __builtin_amdgcn_mfma_f32_16x16x32_bf16(ah, rfl, r1, 0, 0, 0);
      r2 = __builtin_amdgcn_mfma_f32_16x16x32_bf16(am, rfh, r2, 0, 0, 0);
      f32x4 rd = r0 + r1 + r2;
#pragma unroll
      for (int i = 0; i < 4; ++i) r_scr[(w * 16 + gq * 4 + i) * GSTR + fr] = rd[i];
    }
    __syncthreads();
    if (ht < 4 && tid < 512) {
      const int st = cq >> 4, fq = cq & 15;
      float rsum = recb;
#pragma unroll
      for (int kk = 0; kk < 8; ++kk)
        rsum += r_scr[((st * 8 + kk) * 16 + cb) * GSTR + fq];
      __builtin_nontemporal_store(rsum, &out[((size_t)(b0 + cb) * kS + (kS - 1)) * kI + ht * 32 + cq]);
    }
  }
}

extern "C" void kernel_launch(void* const* d_in, const int* in_sizes, int n_in,
                              void* d_out, int out_size, void* d_ws, size_t ws_size,
                              hipStream_t stream) {
  const float* x      = (const float*)d_in[0];
  const float* enc_Wx = (const float*)d_in[1];
  const float* enc_bx = (const float*)d_in[2];
  const float* enc_Wh = (const float*)d_in[3];
  const float* enc_bh = (const float*)d_in[4];
  const float* enc_b  = (const float*)d_in[5];
  const float* dec_Wx = (const float*)d_in[6];
  const float* dec_bx = (const float*)d_in[7];
  const float* dec_Wh = (const float*)d_in[8];
  const float* dec_bh = (const float*)d_in[9];
  const float* dec_b  = (const float*)d_in[10];
  const float* rec_W  = (const float*)d_in[11];
  const float* rec_b  = (const float*)d_in[12];
  float* out = (float*)d_out;

  u64* hx = (u64*)d_ws;

  // zero hx: seq=0 with zero payload == "h_0 = 0 valid" for the first step
  hipMemsetAsync(d_ws, 0, (size_t)WS_HX_U64 * 8, stream);

  hipLaunchKernelGGL(lstm_mfma, dim3(128), dim3(1024), 0, stream,
                     x, enc_Wx, enc_bx, enc_Wh, enc_bh, enc_b,
                     dec_Wx, dec_bx, dec_Wh, dec_bh, dec_b,
                     rec_W, rec_b, out, hx);
}

// Round 16
// 4221.072 us; speedup vs baseline: 1.4573x; 1.4573x over previous
//
#include <hip/hip_runtime.h>
#include <cmath>

#define kB 256
#define kS 512
#define kI 128
#define kH 256

typedef __attribute__((ext_vector_type(8))) short short8;
typedef __attribute__((ext_vector_type(4))) short short4v;
typedef __attribute__((ext_vector_type(4))) float f32x4;
typedef unsigned long long u64;

#define AS_STRIDE 408  // bf16 elems; row stride 816B

// ws: hx u64[2 parity][16 grp][16 b][256 hh] = 1 MiB.
//   u64 = (seq16 << 48) | (hi << 32) | (mid << 16) | lo   (producer-packed split)
#define WS_HX_U64 (2 * 16 * 16 * 256)

__device__ __forceinline__ float sigmoidf_(float z) { return 1.0f / (1.0f + expf(-z)); }

__device__ __forceinline__ unsigned short f2b(float f) {
  unsigned u = __builtin_bit_cast(unsigned, f);
  unsigned r = (u + 0x7fffu + ((u >> 16) & 1u)) >> 16;
  return (unsigned short)r;
}
__device__ __forceinline__ float b2f(unsigned short s) {
  unsigned u = ((unsigned)s) << 16;
  return __builtin_bit_cast(float, u);
}
__device__ __forceinline__ void bsplit2(float f, unsigned short& h_, unsigned short& l_) {
  h_ = f2b(f);
  l_ = f2b(f - b2f(h_));
}
__device__ __forceinline__ void bsplit3(float f, unsigned short& h_, unsigned short& m_, unsigned short& l_) {
  h_ = f2b(f);
  float r1 = f - b2f(h_);
  m_ = f2b(r1);
  l_ = f2b(r1 - b2f(m_));
}

// Coalesced transposed poll of 8 rows at one column; batched stale-retry.
__device__ __forceinline__ void pollrow8(const u64* grp, int col, int rbase,
                                         unsigned seq16, u64* u) {
  unsigned miss = 0xffu;
  for (;;) {
    unsigned nm = 0;
#pragma unroll
    for (int j = 0; j < 8; ++j)
      if (miss & (1u << j))
        u[j] = __hip_atomic_load(grp + (size_t)(rbase + j) * 256 + col,
                                 __ATOMIC_RELAXED, __HIP_MEMORY_SCOPE_SYSTEM);
#pragma unroll
    for (int j = 0; j < 8; ++j)
      if ((miss & (1u << j)) && (unsigned)(u[j] >> 48) != seq16) nm |= 1u << j;
    if (!nm) return;
    miss = nm;
    __builtin_amdgcn_s_sleep(1);
  }
}

// 8-wave block (512 thr), group = 8 blocks (straggler domain 8).  [r13 base]
// Wave w = (gate g=w&3, hh-subtile w>>2). Encoder x-GEMM (ksteps 0..3) issues
// BEFORE the h-poll so it retires in the poll's latency shadow.
__launch_bounds__(512, 2)
__global__ void lstm_mfma(const float* __restrict__ x,
                          const float* __restrict__ enc_Wx, const float* __restrict__ enc_bx,
                          const float* __restrict__ enc_Wh, const float* __restrict__ enc_bh,
                          const float* __restrict__ enc_b,
                          const float* __restrict__ dec_Wx, const float* __restrict__ dec_bx,
                          const float* __restrict__ dec_Wh, const float* __restrict__ dec_bh,
                          const float* __restrict__ dec_b,
                          const float* __restrict__ rec_W, const float* __restrict__ rec_b,
                          float* __restrict__ out,
                          u64* __restrict__ hx) {
  __shared__ __align__(16) short As_h[16 * AS_STRIDE];
  __shared__ __align__(16) short As_m[16 * AS_STRIDE];
  __shared__ __align__(16) short As_l[16 * AS_STRIDE];
  __shared__ float g_scr[8 * 16 * 17];
  __shared__ float r_scr[8 * 16 * 17];
  __shared__ float red[16][32];
  __shared__ float maskS[16];

  const int tid = threadIdx.x;
  // XCD-colocating decode: group bt = blocks ≡ bt (mod 16) -> same XCD under
  // round-robin. Pure perf; protocol stays system-scope.
  const int bt = blockIdx.x & 15;   // b-group (16 rows each)
  const int ht = blockIdx.x >> 4;   // hh-slice (0..7, 32 hh each)
  const int b0 = bt << 4, hh0 = ht << 5;
  const int w  = tid >> 6;          // wave 0..7: gate w&3, hh-subtile w>>2
  const int l  = tid & 63;
  const int fr = l & 15;            // MFMA frag row/col
  const int gq = l >> 4;            // MFMA k-subgroup
  const int cb = tid >> 5;          // cell: local b row (0..15)
  const int cq = tid & 31;          // cell: hh-local (0..31)
  const int hhc = hh0 + cq;
  const int col  = tid & 255;       // staging: column
  const int rbase = (tid >> 8) * 8; // staging: 8-row half

  // ---- combined biases (per cell thread) ----
  float be0 = enc_bx[0*kH+hhc] + enc_bh[0*kH+hhc] + enc_b[0*kH+hhc];
  float be1 = enc_bx[1*kH+hhc] + enc_bh[1*kH+hhc] + enc_b[1*kH+hhc];
  float be2 = enc_bx[2*kH+hhc] + enc_bh[2*kH+hhc] + enc_b[2*kH+hhc];
  float be3 = enc_bx[3*kH+hhc] + enc_bh[3*kH+hhc] + enc_b[3*kH+hhc];
  float bd0 = dec_bx[0*kH+hhc] + dec_bh[0*kH+hhc] + dec_b[0*kH+hhc];
  float bd1 = dec_bx[1*kH+hhc] + dec_bh[1*kH+hhc] + dec_b[1*kH+hhc];
  float bd2 = dec_bx[2*kH+hhc] + dec_bh[2*kH+hhc] + dec_b[2*kH+hhc];
  float bd3 = dec_bx[3*kH+hhc] + dec_bh[3*kH+hhc] + dec_b[3*kH+hhc];
  float recb = (ht < 4) ? rec_b[ht * 32 + cq] : 0.0f;
  float creg = 0.0f;  // cell state, fp32, register-resident

  // ---- encoder weight fragments (bf16 3-way split), K=384 cat [Wx|Wh] ----
  const int g  = w & 3;                       // gate
  const int hw = hh0 + ((w >> 2) << 4) + fr;  // weight row (hh)
  short8 wfh[12], wfm[12], wfl[12];
#pragma unroll
  for (int kst = 0; kst < 12; ++kst) {
    int k = kst * 32 + gq * 8;
    const float* src = (k < 128)
        ? (enc_Wx + ((size_t)(g * kH) + hw) * kI + k)
        : (enc_Wh + ((size_t)(g * kH) + hw) * kH + (k - 128));
    short8 hi, mi, lo;
#pragma unroll
    for (int j = 0; j < 8; ++j) {
      unsigned short h_, m_, l_;
      bsplit3(src[j], h_, m_, l_);
      hi[j] = (short)h_; mi[j] = (short)m_; lo[j] = (short)l_;
    }
    wfh[kst] = hi; wfm[kst] = mi; wfl[kst] = lo;
  }

  // ================= encoder: 512 steps =================
  for (int s = 0; s < kS; ++s) {
    const int par = s & 1;
    // stage x: ALL 512 threads, 4 floats each (row tid>>5, cols (tid&31)*4)
    {
      const int xb = tid >> 5, xc = (tid & 31) * 4;
      const float* xp = x + ((size_t)(b0 + xb) * kS + s) * kI + xc;
      float4 xv = *(const float4*)xp;
      float arr[4] = {xv.x, xv.y, xv.z, xv.w};
      short4v hv, mv, lv;
      float ss = 0.f;
#pragma unroll
      for (int j = 0; j < 4; ++j) {
        float v = arr[j];
        ss += v * v;
        unsigned short h_, m_, l_;
        bsplit3(v, h_, m_, l_);
        hv[j] = (short)h_; mv[j] = (short)m_; lv[j] = (short)l_;
      }
      *(short4v*)(As_h + xb * AS_STRIDE + xc) = hv;
      *(short4v*)(As_m + xb * AS_STRIDE + xc) = mv;
      *(short4v*)(As_l + xb * AS_STRIDE + xc) = lv;
      red[xb][tid & 31] = ss;
    }
    __syncthreads();  // Bx: x region of As staged
    // x-part GEMM (ksteps 0..3) issues NOW, retires under the h-poll latency
    f32x4 a0 = {0.f,0.f,0.f,0.f}, a1 = a0, a2 = a0, a3 = a0, a4 = a0, a5 = a0;
#pragma unroll
    for (int kst = 0; kst < 4; ++kst) {
      const short8 ah = *(const short8*)(As_h + fr * AS_STRIDE + kst * 32 + gq * 8);
      const short8 am = *(const short8*)(As_m + fr * AS_STRIDE + kst * 32 + gq * 8);
      const short8 al = *(const short8*)(As_l + fr * AS_STRIDE + kst * 32 + gq * 8);
      a0 = __builtin_amdgcn_mfma_f32_16x16x32_bf16(ah, wfh[kst], a0, 0, 0, 0);
      a1 = __builtin_amdgcn_mfma_f32_16x16x32_bf16(ah, wfm[kst], a1, 0, 0, 0);
      a2 = __builtin_amdgcn_mfma_f32_16x16x32_bf16(am, wfh[kst], a2, 0, 0, 0);
      a3 = __builtin_amdgcn_mfma_f32_16x16x32_bf16(ah, wfl[kst], a3, 0, 0, 0);
      a4 = __builtin_amdgcn_mfma_f32_16x16x32_bf16(am, wfm[kst], a4, 0, 0, 0);
      a5 = __builtin_amdgcn_mfma_f32_16x16x32_bf16(al, wfh[kst], a5, 0, 0, 0);
    }
    // stage h: coalesced poll of producer-packed splits (8 rows per thread)
    {
      const u64* grp = hx + ((size_t)(par * 16 + bt) * 16) * 256;
      u64 u[8];
      pollrow8(grp, col, rbase, (unsigned)(s & 0xffff), u);
#pragma unroll
      for (int j = 0; j < 8; ++j) {
        As_h[(rbase + j) * AS_STRIDE + 128 + col] = (short)(unsigned short)(u[j] >> 32);
        As_m[(rbase + j) * AS_STRIDE + 128 + col] = (short)(unsigned short)(u[j] >> 16);
        As_l[(rbase + j) * AS_STRIDE + 128 + col] = (short)(unsigned short)(u[j]);
      }
    }
    __syncthreads();  // B: h region staged
    if (tid < 16) {
      float ss = 0.f;
#pragma unroll
      for (int j = 0; j < 32; ++j) ss += red[tid][j];
      maskS[tid] = (ss > 1e-6f) ? 1.0f : 0.0f;
    }
    // h-part GEMM (ksteps 4..11) — same acc chains, same order as r13
#pragma unroll
    for (int kst = 4; kst < 12; ++kst) {
      const short8 ah = *(const short8*)(As_h + fr * AS_STRIDE + kst * 32 + gq * 8);
      const short8 am = *(const short8*)(As_m + fr * AS_STRIDE + kst * 32 + gq * 8);
      const short8 al = *(const short8*)(As_l + fr * AS_STRIDE + kst * 32 + gq * 8);
      a0 = __builtin_amdgcn_mfma_f32_16x16x32_bf16(ah, wfh[kst], a0, 0, 0, 0);
      a1 = __builtin_amdgcn_mfma_f32_16x16x32_bf16(ah, wfm[kst], a1, 0, 0, 0);
      a2 = __builtin_amdgcn_mfma_f32_16x16x32_bf16(am, wfh[kst], a2, 0, 0, 0);
      a3 = __builtin_amdgcn_mfma_f32_16x16x32_bf16(ah, wfl[kst], a3, 0, 0, 0);
      a4 = __builtin_amdgcn_mfma_f32_16x16x32_bf16(am, wfm[kst], a4, 0, 0, 0);
      a5 = __builtin_amdgcn_mfma_f32_16x16x32_bf16(al, wfh[kst], a5, 0, 0, 0);
    }
    f32x4 d = (((a5 + a4) + a3) + (a2 + a1)) + a0;
#pragma unroll
    for (int i = 0; i < 4; ++i) g_scr[(w * 16 + gq * 4 + i) * 17 + fr] = d[i];
    __syncthreads();  // C
    // cell update (thread owns (cb, hhc)); producer splits once and publishes
    {
      const int hsub = (cq >> 4) * 4, fq = cq & 15;
      float gf = g_scr[((0 + hsub) * 16 + cb) * 17 + fq] + be0;
      float gi = g_scr[((1 + hsub) * 16 + cb) * 17 + fq] + be1;
      float go = g_scr[((2 + hsub) * 16 + cb) * 17 + fq] + be2;
      float gc = g_scr[((3 + hsub) * 16 + cb) * 17 + fq] + be3;
      float m  = maskS[cb];
      float f_ = sigmoidf_(gf), i_ = sigmoidf_(gi), o_ = sigmoidf_(go);
      float ct = tanhf(gc);
      creg = (f_ + i_) * creg + m * (i_ * ct);
      float hval = o_ * tanhf(creg);
      unsigned short hb, mb2, lb;
      bsplit3(hval, hb, mb2, lb);
      u64 pk = ((u64)(unsigned)((s + 1) & 0xffff) << 48) | ((u64)hb << 32) | ((u64)mb2 << 16) | (u64)lb;
      size_t wi = (((size_t)(((s + 1) & 1) * 16 + bt) * 16 + cb) * 256) + hhc;
      __hip_atomic_store(hx + wi, pk, __ATOMIC_RELAXED, __HIP_MEMORY_SCOPE_SYSTEM);
    }
  }

  // ---- decoder weights: wdc = dec_Wx + dec_Wh (K=256, 3-way) ----
  short8 dwh[8], dwm[8], dwl[8];
#pragma unroll
  for (int kst = 0; kst < 8; ++kst) {
    int k = kst * 32 + gq * 8;
    const float* s1 = dec_Wx + ((size_t)(g * kH) + hw) * kH + k;
    const float* s2 = dec_Wh + ((size_t)(g * kH) + hw) * kH + k;
    short8 hi, mi, lo;
#pragma unroll
    for (int j = 0; j < 8; ++j) {
      unsigned short h_, m_, l_;
      bsplit3(s1[j] + s2[j], h_, m_, l_);
      hi[j] = (short)h_; mi[j] = (short)m_; lo[j] = (short)l_;
    }
    dwh[kst] = hi; dwm[kst] = mi; dwl[kst] = lo;
  }
  // rec weights (ht<4): wave w -> col-subtile w>>2, kstep pair {2*(w&3), 2*(w&3)+1}
  short8 rfh[2], rfl[2];
#pragma unroll
  for (int kk = 0; kk < 2; ++kk) {
    short8 hi = {0,0,0,0,0,0,0,0}, lo = hi;
    if (ht < 4) {
      int k = (2 * (w & 3) + kk) * 32 + gq * 8;
      const float* src = rec_W + ((size_t)(ht * 32 + ((w >> 2) << 4) + fr)) * kH + k;
#pragma unroll
      for (int j = 0; j < 8; ++j) {
        unsigned short h_, l_;
        bsplit2(src[j], h_, l_);
        hi[j] = (short)h_; lo[j] = (short)l_;
      }
    }
    rfh[kk] = hi; rfl[kk] = lo;
  }

  // ================= decoder: 512 steps =================
  for (int t = 0; t < kS; ++t) {
    const int s = kS + t;
    const int par = s & 1;
    // stage h coalesced (col offset 0)
    {
      const u64* grp = hx + ((size_t)(par * 16 + bt) * 16) * 256;
      u64 u[8];
      pollrow8(grp, col, rbase, (unsigned)(s & 0xffff), u);
#pragma unroll
      for (int j = 0; j < 8; ++j) {
        As_h[(rbase + j) * AS_STRIDE + col] = (short)(unsigned short)(u[j] >> 32);
        As_m[(rbase + j) * AS_STRIDE + col] = (short)(unsigned short)(u[j] >> 16);
        As_l[(rbase + j) * AS_STRIDE + col] = (short)(unsigned short)(u[j]);
      }
    }
    __syncthreads();  // B1: As complete
    // silence-mask partials: 512 threads x 8 elems from LDS reconstruction
    {
      const int mb = tid >> 5, c0 = (tid & 31) * 8;
      const short8 hv = *(const short8*)(As_h + mb * AS_STRIDE + c0);
      const short8 mv = *(const short8*)(As_m + mb * AS_STRIDE + c0);
      const short8 lv = *(const short8*)(As_l + mb * AS_STRIDE + c0);
      float ss = 0.f;
#pragma unroll
      for (int j = 0; j < 8; ++j) {
        float v = b2f((unsigned short)hv[j]) + b2f((unsigned short)mv[j]) + b2f((unsigned short)lv[j]);
        ss += v * v;
      }
      red[mb][tid & 31] = ss;
    }
    __syncthreads();  // B2: red complete
    if (tid < 16) {
      float ss = 0.f;
#pragma unroll
      for (int j = 0; j < 32; ++j) ss += red[tid][j];
      maskS[tid] = (ss > 1e-6f) ? 1.0f : 0.0f;
    }
    // gate GEMM K=256, 6-term scheme
    f32x4 a0 = {0.f,0.f,0.f,0.f}, a1 = a0, a2 = a0, a3 = a0, a4 = a0, a5 = a0;
#pragma unroll
    for (int kst = 0; kst < 8; ++kst) {
      const short8 ah = *(const short8*)(As_h + fr * AS_STRIDE + kst * 32 + gq * 8);
      const short8 am = *(const short8*)(As_m + fr * AS_STRIDE + kst * 32 + gq * 8);
      const short8 al = *(const short8*)(As_l + fr * AS_STRIDE + kst * 32 + gq * 8);
      a0 = __builtin_amdgcn_mfma_f32_16x16x32_bf16(ah, dwh[kst], a0, 0, 0, 0);
      a1 = __builtin_amdgcn_mfma_f32_16x16x32_bf16(ah, dwm[kst], a1, 0, 0, 0);
      a2 = __builtin_amdgcn_mfma_f32_16x16x32_bf16(am, dwh[kst], a2, 0, 0, 0);
      a3 = __builtin_amdgcn_mfma_f32_16x16x32_bf16(ah, dwl[kst], a3, 0, 0, 0);
      a4 = __builtin_amdgcn_mfma_f32_16x16x32_bf16(am, dwm[kst], a4, 0, 0, 0);
      a5 = __builtin_amdgcn_mfma_f32_16x16x32_bf16(al, dwh[kst], a5, 0, 0, 0);
    }
    f32x4 d = (((a5 + a4) + a3) + (a2 + a1)) + a0;
#pragma unroll
    for (int i = 0; i < 4; ++i) g_scr[(w * 16 + gq * 4 + i) * 17 + fr] = d[i];
    // rec GEMM on staged h_(t-1): wave w covers ksteps {2w, 2w+1} (no amplification)
    if (ht < 4) {
      f32x4 r0 = {0.f,0.f,0.f,0.f}, r1 = r0, r2 = r0;
#pragma unroll
      for (int kk = 0; kk < 2; ++kk) {
        const short8 ah = *(const short8*)(As_h + fr * AS_STRIDE + (2 * (w & 3) + kk) * 32 + gq * 8);
        const short8 am = *(const short8*)(As_m + fr * AS_STRIDE + (2 * (w & 3) + kk) * 32 + gq * 8);
        r0 = __builtin_amdgcn_mfma_f32_16x16x32_bf16(ah, rfh[kk], r0, 0, 0, 0);
        r1 = __builtin_amdgcn_mfma_f32_16x16x32_bf16(ah, rfl[kk], r1, 0, 0, 0);
        r2 = __builtin_amdgcn_mfma_f32_16x16x32_bf16(am, rfh[kk], r2, 0, 0, 0);
      }
      f32x4 rd = r0 + r1 + r2;
#pragma unroll
      for (int i = 0; i < 4; ++i) r_scr[(w * 16 + gq * 4 + i) * 17 + fr] = rd[i];
    }
    __syncthreads();  // C
    // cell update + packed-split publish
    {
      const int hsub = (cq >> 4) * 4, fq = cq & 15;
      float gf = g_scr[((0 + hsub) * 16 + cb) * 17 + fq] + bd0;
      float gi = g_scr[((1 + hsub) * 16 + cb) * 17 + fq] + bd1;
      float go = g_scr[((2 + hsub) * 16 + cb) * 17 + fq] + bd2;
      float gc = g_scr[((3 + hsub) * 16 + cb) * 17 + fq] + bd3;
      float m  = maskS[cb];
      float f_ = sigmoidf_(gf), i_ = sigmoidf_(gi), o_ = sigmoidf_(go);
      float ct = tanhf(gc);
      creg = (f_ + i_) * creg + m * (i_ * ct);
      float hval = o_ * tanhf(creg);
      unsigned short hb, mb2, lb;
      bsplit3(hval, hb, mb2, lb);
      u64 pk = ((u64)(unsigned)((s + 1) & 0xffff) << 48) | ((u64)hb << 32) | ((u64)mb2 << 16) | (u64)lb;
      size_t wi = (((size_t)(((s + 1) & 1) * 16 + bt) * 16 + cb) * 256) + hhc;
      __hip_atomic_store(hx + wi, pk, __ATOMIC_RELAXED, __HIP_MEMORY_SCOPE_SYSTEM);
    }
    // reconstruct out[:, t-1, :] (sum the 4 kstep-pair waves of this col-subtile)
    if (ht < 4 && t > 0) {
      const int c2 = cq >> 4, fq = cq & 15;
      float rsum = r_scr[((c2 * 4 + 0) * 16 + cb) * 17 + fq]
                 + r_scr[((c2 * 4 + 1) * 16 + cb) * 17 + fq]
                 + r_scr[((c2 * 4 + 2) * 16 + cb) * 17 + fq]
                 + r_scr[((c2 * 4 + 3) * 16 + cb) * 17 + fq] + recb;
      __builtin_nontemporal_store(rsum, &out[((size_t)(b0 + cb) * kS + (t - 1)) * kI + ht * 32 + cq]);
    }
  }

  // ================= final rec: out[:, 511, :] from h_dec_511 =================
  {
    {
      const u64* grp = hx + ((size_t)(0 * 16 + bt) * 16) * 256;
      u64 u[8];
      pollrow8(grp, col, rbase, (unsigned)((2 * kS) & 0xffff), u);
#pragma unroll
      for (int j = 0; j < 8; ++j) {
        As_h[(rbase + j) * AS_STRIDE + col] = (short)(unsigned short)(u[j] >> 32);
        As_m[(rbase + j) * AS_STRIDE + col] = (short)(unsigned short)(u[j] >> 16);
      }
    }
    __syncthreads();
    if (ht < 4) {
      f32x4 r0 = {0.f,0.f,0.f,0.f}, r1 = r0, r2 = r0;
#pragma unroll
      for (int kk = 0; kk < 2; ++kk) {
        const short8 ah = *(const short8*)(As_h + fr * AS_STRIDE + (2 * (w & 3) + kk) * 32 + gq * 8);
        const short8 am = *(const short8*)(As_m + fr * AS_STRIDE + (2 * (w & 3) + kk) * 32 + gq * 8);
        r0 = __builtin_amdgcn_mfma_f32_16x16x32_bf16(ah, rfh[kk], r0, 0, 0, 0);
        r1 = __builtin_amdgcn_mfma_f32_16x16x32_bf16(ah, rfl[kk], r1, 0, 0, 0);
        r2 = __builtin_amdgcn_mfma_f32_16x16x32_bf16(am, rfh[kk], r2, 0, 0, 0);
      }
      f32x4 rd = r0 + r1 + r2;
#pragma unroll
      for (int i = 0; i < 4; ++i) r_scr[(w * 16 + gq * 4 + i) * 17 + fr] = rd[i];
    }
    __syncthreads();
    if (ht < 4) {
      const int c2 = cq >> 4, fq = cq & 15;
      float rsum = r_scr[((c2 * 4 + 0) * 16 + cb) * 17 + fq]
                 + r_scr[((c2 * 4 + 1) * 16 + cb) * 17 + fq]
                 + r_scr[((c2 * 4 + 2) * 16 + cb) * 17 + fq]
                 + r_scr[((c2 * 4 + 3) * 16 + cb) * 17 + fq] + recb;
      __builtin_nontemporal_store(rsum, &out[((size_t)(b0 + cb) * kS + (kS - 1)) * kI + ht * 32 + cq]);
    }
  }
}

extern "C" void kernel_launch(void* const* d_in, const int* in_sizes, int n_in,
                              void* d_out, int out_size, void* d_ws, size_t ws_size,
                              hipStream_t stream) {
  const float* x      = (const float*)d_in[0];
  const float* enc_Wx = (const float*)d_in[1];
  const float* enc_bx = (const float*)d_in[2];
  const float* enc_Wh = (const float*)d_in[3];
  const float* enc_bh = (const float*)d_in[4];
  const float* enc_b  = (const float*)d_in[5];
  const float* dec_Wx = (const float*)d_in[6];
  const float* dec_bx = (const float*)d_in[7];
  const float* dec_Wh = (const float*)d_in[8];
  const float* dec_bh = (const float*)d_in[9];
  const float* dec_b  = (const float*)d_in[10];
  const float* rec_W  = (const float*)d_in[11];
  const float* rec_b  = (const float*)d_in[12];
  float* out = (float*)d_out;

  u64* hx = (u64*)d_ws;

  // zero hx: seq=0 with zero payload == "h_0 = 0 valid" for the first step
  hipMemsetAsync(d_ws, 0, (size_t)WS_HX_U64 * 8, stream);

  hipLaunchKernelGGL(lstm_mfma, dim3(128), dim3(512), 0, stream,
                     x, enc_Wx, enc_bx, enc_Wh, enc_bh, enc_b,
                     dec_Wx, dec_bx, dec_Wh, dec_bh, dec_b,
                     rec_W, rec_b, out, hx);
}

// Round 17
// 3756.230 us; speedup vs baseline: 1.6376x; 1.1238x over previous
//
#include <hip/hip_runtime.h>
#include <cmath>

#define kB 256
#define kS 512
#define kI 128
#define kH 256

typedef __attribute__((ext_vector_type(8))) short short8;
typedef __attribute__((ext_vector_type(4))) float f32x4;
typedef unsigned long long u64;

#define AS_STRIDE 408  // bf16 elems; row stride 816B

// ws: hx u64[2 parity][16 grp][16 b][256 hh] = 1 MiB. Each element carries its
// own validity AND the producer-computed 3-way bf16 split:
//   u64 = (seq16 << 48) | (hi << 32) | (mid << 16) | lo
#define WS_HX_U64 (2 * 16 * 16 * 256)

__device__ __forceinline__ float sigmoidf_(float z) { return 1.0f / (1.0f + expf(-z)); }

// f32 -> bf16 RNE
__device__ __forceinline__ unsigned short f2b(float f) {
  unsigned u = __builtin_bit_cast(unsigned, f);
  unsigned r = (u + 0x7fffu + ((u >> 16) & 1u)) >> 16;
  return (unsigned short)r;
}
__device__ __forceinline__ float b2f(unsigned short s) {
  unsigned u = ((unsigned)s) << 16;
  return __builtin_bit_cast(float, u);
}
__device__ __forceinline__ void bsplit2(float f, unsigned short& h_, unsigned short& l_) {
  h_ = f2b(f);
  l_ = f2b(f - b2f(h_));
}
__device__ __forceinline__ void bsplit3(float f, unsigned short& h_, unsigned short& m_, unsigned short& l_) {
  h_ = f2b(f);
  float r1 = f - b2f(h_);
  m_ = f2b(r1);
  l_ = f2b(r1 - b2f(m_));
}

// Coalesced transposed poll of 8 rows at one column; batched stale-retry.
__device__ __forceinline__ void pollrow8(const u64* grp, int col, int rbase,
                                         unsigned seq16, u64* u) {
  unsigned miss = 0xffu;
  for (;;) {
    unsigned nm = 0;
#pragma unroll
    for (int j = 0; j < 8; ++j)
      if (miss & (1u << j))
        u[j] = __hip_atomic_load(grp + (size_t)(rbase + j) * 256 + col,
                                 __ATOMIC_RELAXED, __HIP_MEMORY_SCOPE_SYSTEM);
#pragma unroll
    for (int j = 0; j < 8; ++j)
      if ((miss & (1u << j)) && (unsigned)(u[j] >> 48) != seq16) nm |= 1u << j;
    if (!nm) return;
    miss = nm;
    __builtin_amdgcn_s_sleep(1);
  }
}

// 8-wave block (512 thr), group = 8 blocks (straggler domain 8).
__launch_bounds__(512, 2)
__global__ void lstm_mfma(const float* __restrict__ x,
                          const float* __restrict__ enc_Wx, const float* __restrict__ enc_bx,
                          const float* __restrict__ enc_Wh, const float* __restrict__ enc_bh,
                          const float* __restrict__ enc_b,
                          const float* __restrict__ dec_Wx, const float* __restrict__ dec_bx,
                          const float* __restrict__ dec_Wh, const float* __restrict__ dec_bh,
                          const float* __restrict__ dec_b,
                          const float* __restrict__ rec_W, const float* __restrict__ rec_b,
                          float* __restrict__ out,
                          u64* __restrict__ hx) {
  __shared__ __align__(16) short As_h[16 * AS_STRIDE];
  __shared__ __align__(16) short As_m[16 * AS_STRIDE];
  __shared__ __align__(16) short As_l[16 * AS_STRIDE];
  __shared__ float g_scr[8 * 16 * 17];
  __shared__ float r_scr[8 * 16 * 17];
  __shared__ float red[16][16];
  __shared__ float maskS[16];

  const int tid = threadIdx.x;
  const int bt = blockIdx.x & 15;   // b-group (16 rows each)
  const int ht = blockIdx.x >> 4;   // hh-slice (0..7, 32 hh each)
  const int b0 = bt << 4, hh0 = ht << 5;
  const int w  = tid >> 6;          // wave 0..7: gate w&3, hh-subtile w>>2
  const int l  = tid & 63;
  const int fr = l & 15;            // MFMA frag row/col
  const int gq = l >> 4;            // MFMA k-subgroup
  const int cb = tid >> 5;          // cell: local b row (0..15)
  const int cq = tid & 31;          // cell: hh-local (0..31)
  const int hhc = hh0 + cq;
  const int col  = tid & 255;       // staging: column
  const int rbase = (tid >> 8) * 8; // staging: 8-row half

  // ---- combined biases (per cell thread) ----
  float be0 = enc_bx[0*kH+hhc] + enc_bh[0*kH+hhc] + enc_b[0*kH+hhc];
  float be1 = enc_bx[1*kH+hhc] + enc_bh[1*kH+hhc] + enc_b[1*kH+hhc];
  float be2 = enc_bx[2*kH+hhc] + enc_bh[2*kH+hhc] + enc_b[2*kH+hhc];
  float be3 = enc_bx[3*kH+hhc] + enc_bh[3*kH+hhc] + enc_b[3*kH+hhc];
  float bd0 = dec_bx[0*kH+hhc] + dec_bh[0*kH+hhc] + dec_b[0*kH+hhc];
  float bd1 = dec_bx[1*kH+hhc] + dec_bh[1*kH+hhc] + dec_b[1*kH+hhc];
  float bd2 = dec_bx[2*kH+hhc] + dec_bh[2*kH+hhc] + dec_b[2*kH+hhc];
  float bd3 = dec_bx[3*kH+hhc] + dec_bh[3*kH+hhc] + dec_b[3*kH+hhc];
  float recb = (ht < 4) ? rec_b[ht * 32 + cq] : 0.0f;
  float creg = 0.0f;  // cell state, fp32, register-resident

  // ---- encoder weight fragments (bf16 3-way split), K=384 cat [Wx|Wh] ----
  const int g  = w & 3;                       // gate
  const int hw = hh0 + ((w >> 2) << 4) + fr;  // weight row (hh)
  short8 wfh[12], wfm[12], wfl[12];
#pragma unroll
  for (int kst = 0; kst < 12; ++kst) {
    int k = kst * 32 + gq * 8;
    const float* src = (k < 128)
        ? (enc_Wx + ((size_t)(g * kH) + hw) * kI + k)
        : (enc_Wh + ((size_t)(g * kH) + hw) * kH + (k - 128));
    short8 hi, mi, lo;
#pragma unroll
    for (int j = 0; j < 8; ++j) {
      unsigned short h_, m_, l_;
      bsplit3(src[j], h_, m_, l_);
      hi[j] = (short)h_; mi[j] = (short)m_; lo[j] = (short)l_;
    }
    wfh[kst] = hi; wfm[kst] = mi; wfl[kst] = lo;
  }

  // ================= encoder: 512 steps =================
  for (int s = 0; s < kS; ++s) {
    const int par = s & 1;
    // stage x (tid<256, q<8): 128 threads, 16 values each
    if (tid < 256 && (tid & 15) < 8) {
      const int xb = tid >> 4, xq = tid & 15;
      const float* xp = x + ((size_t)(b0 + xb) * kS + s) * kI + xq * 16;
      float arr[16];
      *(float4*)(arr + 0)  = *(const float4*)(xp + 0);
      *(float4*)(arr + 4)  = *(const float4*)(xp + 4);
      *(float4*)(arr + 8)  = *(const float4*)(xp + 8);
      *(float4*)(arr + 12) = *(const float4*)(xp + 12);
      float ss = 0.f;
      short8 H0, H1, M0, M1, L0, L1;
#pragma unroll
      for (int j = 0; j < 16; ++j) {
        float v = arr[j];
        ss += v * v;
        unsigned short h_, m_, l_;
        bsplit3(v, h_, m_, l_);
        if (j < 8) { H0[j] = (short)h_; M0[j] = (short)m_; L0[j] = (short)l_; }
        else       { H1[j-8] = (short)h_; M1[j-8] = (short)m_; L1[j-8] = (short)l_; }
      }
      *(short8*)(As_h + xb * AS_STRIDE + xq * 16)     = H0;
      *(short8*)(As_h + xb * AS_STRIDE + xq * 16 + 8) = H1;
      *(short8*)(As_m + xb * AS_STRIDE + xq * 16)     = M0;
      *(short8*)(As_m + xb * AS_STRIDE + xq * 16 + 8) = M1;
      *(short8*)(As_l + xb * AS_STRIDE + xq * 16)     = L0;
      *(short8*)(As_l + xb * AS_STRIDE + xq * 16 + 8) = L1;
      red[xb][xq] = ss;
    }
    // stage h: coalesced poll of producer-packed splits (8 rows per thread)
    {
      const u64* grp = hx + ((size_t)(par * 16 + bt) * 16) * 256;
      u64 u[8];
      pollrow8(grp, col, rbase, (unsigned)(s & 0xffff), u);
#pragma unroll
      for (int j = 0; j < 8; ++j) {
        As_h[(rbase + j) * AS_STRIDE + 128 + col] = (short)(unsigned short)(u[j] >> 32);
        As_m[(rbase + j) * AS_STRIDE + 128 + col] = (short)(unsigned short)(u[j] >> 16);
        As_l[(rbase + j) * AS_STRIDE + 128 + col] = (short)(unsigned short)(u[j]);
      }
    }
    __syncthreads();  // B
    if (tid < 16) {
      float ss = 0.f;
#pragma unroll
      for (int j = 0; j < 8; ++j) ss += red[tid][j];
      maskS[tid] = (ss > 1e-6f) ? 1.0f : 0.0f;
    }
    // gate GEMM: K=384, 6-term bf16 scheme
    f32x4 a0 = {0.f,0.f,0.f,0.f}, a1 = a0, a2 = a0, a3 = a0, a4 = a0, a5 = a0;
#pragma unroll
    for (int kst = 0; kst < 12; ++kst) {
      const short8 ah = *(const short8*)(As_h + fr * AS_STRIDE + kst * 32 + gq * 8);
      const short8 am = *(const short8*)(As_m + fr * AS_STRIDE + kst * 32 + gq * 8);
      const short8 al = *(const short8*)(As_l + fr * AS_STRIDE + kst * 32 + gq * 8);
      a0 = __builtin_amdgcn_mfma_f32_16x16x32_bf16(ah, wfh[kst], a0, 0, 0, 0);
      a1 = __builtin_amdgcn_mfma_f32_16x16x32_bf16(ah, wfm[kst], a1, 0, 0, 0);
      a2 = __builtin_amdgcn_mfma_f32_16x16x32_bf16(am, wfh[kst], a2, 0, 0, 0);
      a3 = __builtin_amdgcn_mfma_f32_16x16x32_bf16(ah, wfl[kst], a3, 0, 0, 0);
      a4 = __builtin_amdgcn_mfma_f32_16x16x32_bf16(am, wfm[kst], a4, 0, 0, 0);
      a5 = __builtin_amdgcn_mfma_f32_16x16x32_bf16(al, wfh[kst], a5, 0, 0, 0);
    }
    f32x4 d = (((a5 + a4) + a3) + (a2 + a1)) + a0;
#pragma unroll
    for (int i = 0; i < 4; ++i) g_scr[(w * 16 + gq * 4 + i) * 17 + fr] = d[i];
    __syncthreads();  // C
    // cell update (thread owns (cb, hhc)); producer splits once and publishes
    {
      const int hsub = (cq >> 4) * 4, fq = cq & 15;
      float gf = g_scr[((0 + hsub) * 16 + cb) * 17 + fq] + be0;
      float gi = g_scr[((1 + hsub) * 16 + cb) * 17 + fq] + be1;
      float go = g_scr[((2 + hsub) * 16 + cb) * 17 + fq] + be2;
      float gc = g_scr[((3 + hsub) * 16 + cb) * 17 + fq] + be3;
      float m  = maskS[cb];
      float f_ = sigmoidf_(gf), i_ = sigmoidf_(gi), o_ = sigmoidf_(go);
      float ct = tanhf(gc);
      creg = (f_ + i_) * creg + m * (i_ * ct);
      float hval = o_ * tanhf(creg);
      unsigned short hb, mb2, lb;
      bsplit3(hval, hb, mb2, lb);
      u64 pk = ((u64)(unsigned)((s + 1) & 0xffff) << 48) | ((u64)hb << 32) | ((u64)mb2 << 16) | (u64)lb;
      size_t wi = (((size_t)(((s + 1) & 1) * 16 + bt) * 16 + cb) * 256) + hhc;
      __hip_atomic_store(hx + wi, pk, __ATOMIC_RELAXED, __HIP_MEMORY_SCOPE_SYSTEM);
    }
  }

  // ---- decoder weights: wdc = dec_Wx + dec_Wh (K=256, 3-way) ----
  short8 dwh[8], dwm[8], dwl[8];
#pragma unroll
  for (int kst = 0; kst < 8; ++kst) {
    int k = kst * 32 + gq * 8;
    const float* s1 = dec_Wx + ((size_t)(g * kH) + hw) * kH + k;
    const float* s2 = dec_Wh + ((size_t)(g * kH) + hw) * kH + k;
    short8 hi, mi, lo;
#pragma unroll
    for (int j = 0; j < 8; ++j) {
      unsigned short h_, m_, l_;
      bsplit3(s1[j] + s2[j], h_, m_, l_);
      hi[j] = (short)h_; mi[j] = (short)m_; lo[j] = (short)l_;
    }
    dwh[kst] = hi; dwm[kst] = mi; dwl[kst] = lo;
  }
  // rec weights (ht<4): wave w -> col-subtile w>>2, kstep pair {2*(w&3), 2*(w&3)+1}
  short8 rfh[2], rfl[2];
#pragma unroll
  for (int kk = 0; kk < 2; ++kk) {
    short8 hi = {0,0,0,0,0,0,0,0}, lo = hi;
    if (ht < 4) {
      int k = (2 * (w & 3) + kk) * 32 + gq * 8;
      const float* src = rec_W + ((size_t)(ht * 32 + ((w >> 2) << 4) + fr)) * kH + k;
#pragma unroll
      for (int j = 0; j < 8; ++j) {
        unsigned short h_, l_;
        bsplit2(src[j], h_, l_);
        hi[j] = (short)h_; lo[j] = (short)l_;
      }
    }
    rfh[kk] = hi; rfl[kk] = lo;
  }

  // ================= decoder: 512 steps =================
  for (int t = 0; t < kS; ++t) {
    const int s = kS + t;
    const int par = s & 1;
    // stage h coalesced (col offset 0)
    {
      const u64* grp = hx + ((size_t)(par * 16 + bt) * 16) * 256;
      u64 u[8];
      pollrow8(grp, col, rbase, (unsigned)(s & 0xffff), u);
#pragma unroll
      for (int j = 0; j < 8; ++j) {
        As_h[(rbase + j) * AS_STRIDE + col] = (short)(unsigned short)(u[j] >> 32);
        As_m[(rbase + j) * AS_STRIDE + col] = (short)(unsigned short)(u[j] >> 16);
        As_l[(rbase + j) * AS_STRIDE + col] = (short)(unsigned short)(u[j]);
      }
    }
    __syncthreads();  // B1: As complete
    // silence-mask partials from LDS reconstruction
    if (tid < 256) {
      const int mb = tid >> 4, mq = tid & 15;
      float ss = 0.f;
#pragma unroll
      for (int g2 = 0; g2 < 2; ++g2) {
        const short8 hv = *(const short8*)(As_h + mb * AS_STRIDE + mq * 16 + g2 * 8);
        const short8 mv = *(const short8*)(As_m + mb * AS_STRIDE + mq * 16 + g2 * 8);
        const short8 lv = *(const short8*)(As_l + mb * AS_STRIDE + mq * 16 + g2 * 8);
#pragma unroll
        for (int j = 0; j < 8; ++j) {
          float v = b2f((unsigned short)hv[j]) + b2f((unsigned short)mv[j]) + b2f((unsigned short)lv[j]);
          ss += v * v;
        }
      }
      red[mb][mq] = ss;
    }
    __syncthreads();  // B2: red complete
    if (tid < 16) {
      float ss = 0.f;
#pragma unroll
      for (int j = 0; j < 16; ++j) ss += red[tid][j];
      maskS[tid] = (ss > 1e-6f) ? 1.0f : 0.0f;
    }
    // gate GEMM K=256, 6-term scheme
    f32x4 a0 = {0.f,0.f,0.f,0.f}, a1 = a0, a2 = a0, a3 = a0, a4 = a0, a5 = a0;
#pragma unroll
    for (int kst = 0; kst < 8; ++kst) {
      const short8 ah = *(const short8*)(As_h + fr * AS_STRIDE + kst * 32 + gq * 8);
      const short8 am = *(const short8*)(As_m + fr * AS_STRIDE + kst * 32 + gq * 8);
      const short8 al = *(const short8*)(As_l + fr * AS_STRIDE + kst * 32 + gq * 8);
      a0 = __builtin_amdgcn_mfma_f32_16x16x32_bf16(ah, dwh[kst], a0, 0, 0, 0);
      a1 = __builtin_amdgcn_mfma_f32_16x16x32_bf16(ah, dwm[kst], a1, 0, 0, 0);
      a2 = __builtin_amdgcn_mfma_f32_16x16x32_bf16(am, dwh[kst], a2, 0, 0, 0);
      a3 = __builtin_amdgcn_mfma_f32_16x16x32_bf16(ah, dwl[kst], a3, 0, 0, 0);
      a4 = __builtin_amdgcn_mfma_f32_16x16x32_bf16(am, dwm[kst], a4, 0, 0, 0);
      a5 = __builtin_amdgcn_mfma_f32_16x16x32_bf16(al, dwh[kst], a5, 0, 0, 0);
    }
    f32x4 d = (((a5 + a4) + a3) + (a2 + a1)) + a0;
#pragma unroll
    for (int i = 0; i < 4; ++i) g_scr[(w * 16 + gq * 4 + i) * 17 + fr] = d[i];
    // rec GEMM on staged h_(t-1): wave w covers ksteps {2w, 2w+1} (no amplification)
    if (ht < 4) {
      f32x4 r0 = {0.f,0.f,0.f,0.f}, r1 = r0, r2 = r0;
#pragma unroll
      for (int kk = 0; kk < 2; ++kk) {
        const short8 ah = *(const short8*)(As_h + fr * AS_STRIDE + (2 * (w & 3) + kk) * 32 + gq * 8);
        const short8 am = *(const short8*)(As_m + fr * AS_STRIDE + (2 * (w & 3) + kk) * 32 + gq * 8);
        r0 = __builtin_amdgcn_mfma_f32_16x16x32_bf16(ah, rfh[kk], r0, 0, 0, 0);
        r1 = __builtin_amdgcn_mfma_f32_16x16x32_bf16(ah, rfl[kk], r1, 0, 0, 0);
        r2 = __builtin_amdgcn_mfma_f32_16x16x32_bf16(am, rfh[kk], r2, 0, 0, 0);
      }
      f32x4 rd = r0 + r1 + r2;
#pragma unroll
      for (int i = 0; i < 4; ++i) r_scr[(w * 16 + gq * 4 + i) * 17 + fr] = rd[i];
    }
    __syncthreads();  // C
    // cell update + packed-split publish
    {
      const int hsub = (cq >> 4) * 4, fq = cq & 15;
      float gf = g_scr[((0 + hsub) * 16 + cb) * 17 + fq] + bd0;
      float gi = g_scr[((1 + hsub) * 16 + cb) * 17 + fq] + bd1;
      float go = g_scr[((2 + hsub) * 16 + cb) * 17 + fq] + bd2;
      float gc = g_scr[((3 + hsub) * 16 + cb) * 17 + fq] + bd3;
      float m  = maskS[cb];
      float f_ = sigmoidf_(gf), i_ = sigmoidf_(gi), o_ = sigmoidf_(go);
      float ct = tanhf(gc);
      creg = (f_ + i_) * creg + m * (i_ * ct);
      float hval = o_ * tanhf(creg);
      unsigned short hb, mb2, lb;
      bsplit3(hval, hb, mb2, lb);
      u64 pk = ((u64)(unsigned)((s + 1) & 0xffff) << 48) | ((u64)hb << 32) | ((u64)mb2 << 16) | (u64)lb;
      size_t wi = (((size_t)(((s + 1) & 1) * 16 + bt) * 16 + cb) * 256) + hhc;
      __hip_atomic_store(hx + wi, pk, __ATOMIC_RELAXED, __HIP_MEMORY_SCOPE_SYSTEM);
    }
    // reconstruct out[:, t-1, :] (sum the 4 kstep-pair waves of this col-subtile)
    if (ht < 4 && t > 0) {
      const int c2 = cq >> 4, fq = cq & 15;
      float rsum = r_scr[((c2 * 4 + 0) * 16 + cb) * 17 + fq]
                 + r_scr[((c2 * 4 + 1) * 16 + cb) * 17 + fq]
                 + r_scr[((c2 * 4 + 2) * 16 + cb) * 17 + fq]
                 + r_scr[((c2 * 4 + 3) * 16 + cb) * 17 + fq] + recb;
      __builtin_nontemporal_store(rsum, &out[((size_t)(b0 + cb) * kS + (t - 1)) * kI + ht * 32 + cq]);
    }
  }

  // ================= final rec: out[:, 511, :] from h_dec_511 =================
  {
    {
      const u64* grp = hx + ((size_t)(0 * 16 + bt) * 16) * 256;
      u64 u[8];
      pollrow8(grp, col, rbase, (unsigned)((2 * kS) & 0xffff), u);
#pragma unroll
      for (int j = 0; j < 8; ++j) {
        As_h[(rbase + j) * AS_STRIDE + col] = (short)(unsigned short)(u[j] >> 32);
        As_m[(rbase + j) * AS_STRIDE + col] = (short)(unsigned short)(u[j] >> 16);
      }
    }
    __syncthreads();
    if (ht < 4) {
      f32x4 r0 = {0.f,0.f,0.f,0.f}, r1 = r0, r2 = r0;
#pragma unroll
      for (int kk = 0; kk < 2; ++kk) {
        const short8 ah = *(const short8*)(As_h + fr * AS_STRIDE + (2 * (w & 3) + kk) * 32 + gq * 8);
        const short8 am = *(const short8*)(As_m + fr * AS_STRIDE + (2 * (w & 3) + kk) * 32 + gq * 8);
        r0 = __builtin_amdgcn_mfma_f32_16x16x32_bf16(ah, rfh[kk], r0, 0, 0, 0);
        r1 = __builtin_amdgcn_mfma_f32_16x16x32_bf16(ah, rfl[kk], r1, 0, 0, 0);
        r2 = __builtin_amdgcn_mfma_f32_16x16x32_bf16(am, rfh[kk], r2, 0, 0, 0);
      }
      f32x4 rd = r0 + r1 + r2;
#pragma unroll
      for (int i = 0; i < 4; ++i) r_scr[(w * 16 + gq * 4 + i) * 17 + fr] = rd[i];
    }
    __syncthreads();
    if (ht < 4) {
      const int c2 = cq >> 4, fq = cq & 15;
      float rsum = r_scr[((c2 * 4 + 0) * 16 + cb) * 17 + fq]
                 + r_scr[((c2 * 4 + 1) * 16 + cb) * 17 + fq]
                 + r_scr[((c2 * 4 + 2) * 16 + cb) * 17 + fq]
                 + r_scr[((c2 * 4 + 3) * 16 + cb) * 17 + fq] + recb;
      __builtin_nontemporal_store(rsum, &out[((size_t)(b0 + cb) * kS + (kS - 1)) * kI + ht * 32 + cq]);
    }
  }
}

extern "C" void kernel_launch(void* const* d_in, const int* in_sizes, int n_in,
                              void* d_out, int out_size, void* d_ws, size_t ws_size,
                              hipStream_t stream) {
  const float* x      = (const float*)d_in[0];
  const float* enc_Wx = (const float*)d_in[1];
  const float* enc_bx = (const float*)d_in[2];
  const float* enc_Wh = (const float*)d_in[3];
  const float* enc_bh = (const float*)d_in[4];
  const float* enc_b  = (const float*)d_in[5];
  const float* dec_Wx = (const float*)d_in[6];
  const float* dec_bx = (const float*)d_in[7];
  const float* dec_Wh = (const float*)d_in[8];
  const float* dec_bh = (const float*)d_in[9];
  const float* dec_b  = (const float*)d_in[10];
  const float* rec_W  = (const float*)d_in[11];
  const float* rec_b  = (const float*)d_in[12];
  float* out = (float*)d_out;

  u64* hx = (u64*)d_ws;

  // zero hx: seq=0 with zero payload == "h_0 = 0 valid" for the first step
  hipMemsetAsync(d_ws, 0, (size_t)WS_HX_U64 * 8, stream);

  hipLaunchKernelGGL(lstm_mfma, dim3(128), dim3(512), 0, stream,
                     x, enc_Wx, enc_bx, enc_Wh, enc_bh, enc_b,
                     dec_Wx, dec_bx, dec_Wh, dec_bh, dec_b,
                     rec_W, rec_b, out, hx);
}